// Round 4
// baseline (73.645 us; speedup 1.0000x reference)
//
#include <hip/hip_runtime.h>

#define NB 16     // batches
#define NV 19     // vertices
#define NE 361    // edges per graph
#define NL 256    // seq len
#define ND 64     // d_model
#define NT 23     // edge tiles of 16 (ceil(361/16))
#define NEP (NT * 16)   // 368 padded edges
#define ASTR 132  // f32 elems per A row: 528B, 16B-aligned, banks spread v*4

typedef __attribute__((ext_vector_type(8))) short bf16x8;
typedef __attribute__((ext_vector_type(4))) float f32x4;
typedef __attribute__((ext_vector_type(2))) __bf16 bf16v2;

union bf8u { unsigned u[4]; bf16x8 v; uint4 q; };

__device__ __forceinline__ unsigned pack_bf16(float lo, float hi) {
    bf16v2 v; v.x = (__bf16)lo; v.y = (__bf16)hi;   // -> v_cvt_pk_bf16_f32
    return __builtin_bit_cast(unsigned, v);
}
__device__ __forceinline__ short f2bf(float f) {
    __bf16 h = (__bf16)f;
    return __builtin_bit_cast(short, h);
}
// packed-f32-friendly 4-wide silu: x * rcp(1 + exp2(-x*log2e))
__device__ __forceinline__ f32x4 silu4(f32x4 x) {
    f32x4 t = x * -1.44269504f;                     // 2x v_pk_mul_f32
    f32x4 d;
    d.x = __builtin_amdgcn_exp2f(t.x);
    d.y = __builtin_amdgcn_exp2f(t.y);
    d.z = __builtin_amdgcn_exp2f(t.z);
    d.w = __builtin_amdgcn_exp2f(t.w);
    d += 1.f;                                       // 2x v_pk_add_f32
    f32x4 r;
    r.x = __builtin_amdgcn_rcpf(d.x);
    r.y = __builtin_amdgcn_rcpf(d.y);
    r.z = __builtin_amdgcn_rcpf(d.z);
    r.w = __builtin_amdgcn_rcpf(d.w);
    return x * r;                                   // 2x v_pk_mul_f32
}
__device__ __forceinline__ float sigm(float x) {
    return __builtin_amdgcn_rcpf(1.f + __builtin_amdgcn_exp2f(x * -1.44269504f));
}

// One block per (b, l). 256 threads = 4 waves.
__global__ __launch_bounds__(256, 4) void edge_learner_kernel(
    const float* __restrict__ hs,      // (B*V, L, D)
    const float* __restrict__ ew_in,   // (B*E, L)
    const float* __restrict__ W1,      // (129, 64)
    const float* __restrict__ b1,      // (64,)
    const float* __restrict__ W2,      // (64, 32)
    const float* __restrict__ b2,      // (32,)
    const float* __restrict__ W3,      // (32, 1)
    const float* __restrict__ b3,      // (1,)
    const float* __restrict__ skip_p,  // (1,)
    const int*   __restrict__ eidx,    // (2, B*E, L)
    float* __restrict__ out)           // (B*E, L)
{
    __shared__ __align__(16) float A_s[NV * ASTR];  // node projections, f32
    __shared__ int   srco_s[NEP];   // src*ASTR
    __shared__ int   tgto_s[NEP];   // tgt*ASTR + 64
    __shared__ float ew_s[NEP];

    const int tid  = threadIdx.x;
    const int lane = tid & 63;
    const int wave = tid >> 6;
    const int lq   = lane >> 4;    // quarter (k-group)
    const int lm   = lane & 15;    // row/col within fragment
    // XCD-contiguous swizzle: blocks on one XCD cover contiguous (b,l) range,
    // so 64B eidx/ew/out lines (16 consecutive l) hit one L2. 4096 % 8 == 0.
    const int bid0 = blockIdx.x;
    const int bid  = (bid0 & 7) * 512 + (bid0 >> 3);
    const int b    = bid >> 8;     // bid / NL
    const int l    = bid & 255;    // bid % NL

    // ---------- stage edge metadata ----------
    for (int e = tid; e < NEP; e += 256) {
        if (e < NE) {
            size_t row = (size_t)(b * NE + e) * NL + l;
            srco_s[e] = (eidx[row] % NV) * ASTR;
            tgto_s[e] = (eidx[(size_t)NB * NE * NL + row] % NV) * ASTR + 64;
            ew_s[e]   = ew_in[row];
        } else {
            srco_s[e] = 0; tgto_s[e] = 64; ew_s[e] = 0.f;
        }
    }

    // ---------- per-lane constants (registers) ----------
    // layer-1 channels for this lane: ch(ks,i) = ks*32 + lq*8 + i
    f32x4 w1lv[2][2], b1v[2][2];
    #pragma unroll
    for (int ks = 0; ks < 2; ++ks) {
        w1lv[ks][0] = *(const f32x4*)&W1[128 * 64 + ks * 32 + lq * 8];
        w1lv[ks][1] = *(const f32x4*)&W1[128 * 64 + ks * 32 + lq * 8 + 4];
        b1v[ks][0]  = *(const f32x4*)&b1[ks * 32 + lq * 8];
        b1v[ks][1]  = *(const f32x4*)&b1[ks * 32 + lq * 8 + 4];
    }
    // W2 B-fragments: lane holds col nt*16+lm, k = ks*32+lq*8+i (paired cvt_pk)
    bf8u w2f[2][2];
    #pragma unroll
    for (int nt = 0; nt < 2; ++nt)
        #pragma unroll
        for (int ks = 0; ks < 2; ++ks) {
            const float* w2p = &W2[(ks * 32 + lq * 8) * 32 + nt * 16 + lm];
            #pragma unroll
            for (int p = 0; p < 4; ++p)
                w2f[nt][ks].u[p] = pack_bf16(w2p[(2 * p) * 32], w2p[(2 * p + 1) * 32]);
        }
    const float b2r0 = b2[lm],      b2r1 = b2[16 + lm];
    const float w3a  = W3[lm],      w3b  = W3[16 + lm];
    const float b3v  = b3[0];
    const float skip = skip_p[0];

    // ---------- phase 2: A[v][c] via MFMA; wave w owns cols [32w, 32w+32) ----------
    {
        const int half = wave >> 1;
        const int oc0  = (wave & 1) * 32;
        bf8u w1f[2][2];   // [nt][ks]
        #pragma unroll
        for (int nt = 0; nt < 2; ++nt)
            #pragma unroll
            for (int ks = 0; ks < 2; ++ks) {
                const float* wp = &W1[(half * 64 + ks * 32 + lq * 8) * 64
                                      + oc0 + nt * 16 + lm];
                #pragma unroll
                for (int p = 0; p < 4; ++p)
                    w1f[nt][ks].u[p] = pack_bf16(wp[(2 * p) * 64], wp[(2 * p + 1) * 64]);
            }

        f32x4 acc00 = {0,0,0,0}, acc01 = {0,0,0,0}, acc10 = {0,0,0,0}, acc11 = {0,0,0,0};
        #pragma unroll
        for (int Mt = 0; Mt < 2; ++Mt) {
            int v  = Mt * 16 + lm;
            int vc = v < NV ? v : NV - 1;            // clamp pad rows
            const float* hp = hs + ((size_t)(b * NV + vc) * NL + l) * ND;
            bf8u af[2];
            #pragma unroll
            for (int ks = 0; ks < 2; ++ks) {
                float4 x0 = *(const float4*)&hp[ks * 32 + lq * 8];
                float4 x1 = *(const float4*)&hp[ks * 32 + lq * 8 + 4];
                af[ks].u[0] = pack_bf16(x0.x, x0.y);
                af[ks].u[1] = pack_bf16(x0.z, x0.w);
                af[ks].u[2] = pack_bf16(x1.x, x1.y);
                af[ks].u[3] = pack_bf16(x1.z, x1.w);
            }
            if (Mt == 0) {
                acc00 = __builtin_amdgcn_mfma_f32_16x16x32_bf16(af[0].v, w1f[0][0].v, acc00, 0, 0, 0);
                acc00 = __builtin_amdgcn_mfma_f32_16x16x32_bf16(af[1].v, w1f[0][1].v, acc00, 0, 0, 0);
                acc01 = __builtin_amdgcn_mfma_f32_16x16x32_bf16(af[0].v, w1f[1][0].v, acc01, 0, 0, 0);
                acc01 = __builtin_amdgcn_mfma_f32_16x16x32_bf16(af[1].v, w1f[1][1].v, acc01, 0, 0, 0);
            } else {
                acc10 = __builtin_amdgcn_mfma_f32_16x16x32_bf16(af[0].v, w1f[0][0].v, acc10, 0, 0, 0);
                acc10 = __builtin_amdgcn_mfma_f32_16x16x32_bf16(af[1].v, w1f[0][1].v, acc10, 0, 0, 0);
                acc11 = __builtin_amdgcn_mfma_f32_16x16x32_bf16(af[0].v, w1f[1][0].v, acc11, 0, 0, 0);
                acc11 = __builtin_amdgcn_mfma_f32_16x16x32_bf16(af[1].v, w1f[1][1].v, acc11, 0, 0, 0);
            }
        }
        // write A (f32): row v = Mt*16 + lq*4 + r, col c = wave*32 + {lm, 16+lm}
        #pragma unroll
        for (int r = 0; r < 4; ++r) {
            int v0 = lq * 4 + r;
            A_s[v0 * ASTR + wave * 32 + lm]      = acc00[r];
            A_s[v0 * ASTR + wave * 32 + 16 + lm] = acc01[r];
            int v1 = 16 + lq * 4 + r;
            if (v1 < NV) {
                A_s[v1 * ASTR + wave * 32 + lm]      = acc10[r];
                A_s[v1 * ASTR + wave * 32 + 16 + lm] = acc11[r];
            }
        }
    }
    __syncthreads();

    // ---------- phase 3: edge tiles of 16, one wave per tile ----------
    for (int t = wave; t < NT; t += 4) {
        const int ebase = t * 16;
        const int e  = ebase + lm;        // this lane's edge (layer-1 role)
        const int so = srco_s[e];
        const int to = tgto_s[e];
        const float ew = ew_s[e];

        // per-tile affine term g = ew*w1l + b1 (packed fma)
        f32x4 g00 = ew * w1lv[0][0] + b1v[0][0];
        f32x4 g01 = ew * w1lv[0][1] + b1v[0][1];
        f32x4 g10 = ew * w1lv[1][0] + b1v[1][0];
        f32x4 g11 = ew * w1lv[1][1] + b1v[1][1];

        // layer 1: f32 A reads, packed math, cvt_pk to bf16 fragments
        bf8u a1[2];
        #pragma unroll
        for (int ks = 0; ks < 2; ++ks) {
            f32x4 s0 = *(const f32x4*)&A_s[so + ks * 32 + lq * 8];
            f32x4 s1 = *(const f32x4*)&A_s[so + ks * 32 + lq * 8 + 4];
            f32x4 t0 = *(const f32x4*)&A_s[to + ks * 32 + lq * 8];
            f32x4 t1 = *(const f32x4*)&A_s[to + ks * 32 + lq * 8 + 4];
            f32x4 x0 = s0 + t0 + (ks ? g10 : g00);
            f32x4 x1 = s1 + t1 + (ks ? g11 : g01);
            f32x4 y0 = silu4(x0);
            f32x4 y1 = silu4(x1);
            a1[ks].u[0] = pack_bf16(y0.x, y0.y);
            a1[ks].u[1] = pack_bf16(y0.z, y0.w);
            a1[ks].u[2] = pack_bf16(y1.x, y1.y);
            a1[ks].u[3] = pack_bf16(y1.z, y1.w);
        }

        // layer 2: (16 edges x 64) @ (64 x 32) via 4 MFMAs
        f32x4 c0 = {0,0,0,0}, c1 = {0,0,0,0};
        c0 = __builtin_amdgcn_mfma_f32_16x16x32_bf16(a1[0].v, w2f[0][0].v, c0, 0, 0, 0);
        c0 = __builtin_amdgcn_mfma_f32_16x16x32_bf16(a1[1].v, w2f[0][1].v, c0, 0, 0, 0);
        c1 = __builtin_amdgcn_mfma_f32_16x16x32_bf16(a1[0].v, w2f[1][0].v, c1, 0, 0, 0);
        c1 = __builtin_amdgcn_mfma_f32_16x16x32_bf16(a1[1].v, w2f[1][1].v, c1, 0, 0, 0);

        // epilogue: packed silu over 4 rows, layer-3 partials, butterfly reduce
        f32x4 h0 = silu4(c0 + b2r0);
        f32x4 h1 = silu4(c1 + b2r1);
        f32x4 p  = h0 * w3a + h1 * w3b;
        #pragma unroll
        for (int s = 1; s < 16; s <<= 1) {
            f32x4 q;
            q.x = __shfl_xor(p.x, s);
            q.y = __shfl_xor(p.y, s);
            q.z = __shfl_xor(p.z, s);
            q.w = __shfl_xor(p.w, s);
            p += q;
        }
        // lanes lm<4 store edges: row = lq*4 + (lane&3)
        if (lm < 4) {
            int er = ebase + lq * 4 + (lane & 3);
            if (er < NE) {
                int r = lane & 3;
                float ps = (r & 2) ? ((r & 1) ? p.w : p.z)
                                   : ((r & 1) ? p.y : p.x);
                float wgt = sigm(ps + b3v);
                float ewr = ew_s[er];
                out[(size_t)(b * NE + er) * NL + l] = skip * ewr + (1.f - skip) * wgt;
            }
        }
    }
}

extern "C" void kernel_launch(void* const* d_in, const int* in_sizes, int n_in,
                              void* d_out, int out_size, void* d_ws, size_t ws_size,
                              hipStream_t stream) {
    const float* hs   = (const float*)d_in[0];
    const float* ew   = (const float*)d_in[1];
    const float* W1   = (const float*)d_in[2];
    const float* b1   = (const float*)d_in[3];
    const float* W2   = (const float*)d_in[4];
    const float* b2   = (const float*)d_in[5];
    const float* W3   = (const float*)d_in[6];
    const float* b3   = (const float*)d_in[7];
    const float* skip = (const float*)d_in[8];
    const int*   eidx = (const int*)d_in[9];
    float* outp = (float*)d_out;

    dim3 grid(NB * NL);   // 4096 blocks, one per (b, l)
    dim3 block(256);
    hipLaunchKernelGGL(edge_learner_kernel, grid, block, 0, stream,
                       hs, ew, W1, b1, W2, b2, W3, b3, skip, eidx, outp);
}